// Round 8
// baseline (494.348 us; speedup 1.0000x reference)
//
#include <hip/hip_runtime.h>

// GCN pipeline (R8 = R6 with smaller gemm blocks):
//   k_hist:    per-bucket(256 dst nodes) edge counts, LDS hist
//   k_scanb:   exclusive scan -> bbase[], gcur[]
//   k_binA:    tile-wise LDS counting sort by bucket -> binned[] (src|dstlo<<17)
//   k_sortcsr: per-bucket dstlo hist+scan -> rowptr, dinv; placement -> csr
//   k_gemm:    hsb = pack_bf16((X @ W) * dinv[row]); 128 rows/block (782 blocks,
//              ~3/CU), 2 rows/thread, wave-split cols; W in LDS (broadcast reads)
//   k_agg64n/k_agg32n: wave-per-node uint4 bf16 gather (8/16 rows per load instr)
//   k_classifier: 32->10 + log_softmax

#define BSHIFT 8
#define BMASK 255
#define NBUCK_MAX 512
#define TILE 4096
#define EPT 16             // TILE / 256

__device__ __forceinline__ unsigned pack_bf16(float lo, float hi) {
    unsigned ul = __float_as_uint(lo);
    ul = (ul + 0x7FFFu + ((ul >> 16) & 1u)) >> 16;
    unsigned uh = __float_as_uint(hi);
    uh = ((uh + 0x7FFFu + ((uh >> 16) & 1u)) >> 16) << 16;
    return ul | uh;
}

__global__ void k_hist(const int* __restrict__ dst, int* __restrict__ bcnt, int E) {
    __shared__ int h[NBUCK_MAX];
    for (int i = threadIdx.x; i < NBUCK_MAX; i += blockDim.x) h[i] = 0;
    __syncthreads();
    for (int e = blockIdx.x * blockDim.x + threadIdx.x; e < E; e += gridDim.x * blockDim.x)
        atomicAdd(&h[dst[e] >> BSHIFT], 1);
    __syncthreads();
    for (int i = threadIdx.x; i < NBUCK_MAX; i += blockDim.x)
        if (h[i]) atomicAdd(&bcnt[i], h[i]);
}

__global__ void k_scanb(const int* __restrict__ bcnt, int* __restrict__ bbase,
                        int* __restrict__ gcur, int E) {
    __shared__ int s[NBUCK_MAX];
    int t = threadIdx.x;
    int v = bcnt[t];
    s[t] = v;
    __syncthreads();
    for (int o = 1; o < NBUCK_MAX; o <<= 1) {
        int u = (t >= o) ? s[t - o] : 0;
        __syncthreads();
        s[t] += u;
        __syncthreads();
    }
    int ex = s[t] - v;
    bbase[t] = ex;
    gcur[t] = ex;
    if (t == NBUCK_MAX - 1) bbase[NBUCK_MAX] = E;
}

// Tile-wise LDS counting sort by bucket; dump contiguous per-bucket runs.
__global__ __launch_bounds__(256) void k_binA(const int* __restrict__ src,
                                              const int* __restrict__ dst,
                                              int* __restrict__ gcur,
                                              int* __restrict__ binned, int E) {
    __shared__ int hist[NBUCK_MAX];
    __shared__ int lbase[NBUCK_MAX];
    __shared__ int gdelta[NBUCK_MAX];
    __shared__ int cnt2[NBUCK_MAX];
    __shared__ int scanb[256];
    __shared__ int stage[TILE];
    __shared__ unsigned short sbucket[TILE];

    int t = threadIdx.x;
    for (int i = t; i < NBUCK_MAX; i += 256) { hist[i] = 0; cnt2[i] = 0; }
    __syncthreads();

    int tileStart = blockIdx.x * TILE;
    int cntTile = min(TILE, E - tileStart);

    int vals[EPT];
    int bks[EPT];
#pragma unroll
    for (int i = 0; i < EPT; i++) {
        int e = tileStart + t + i * 256;
        if (e < E) {
            int s = src[e], d = dst[e];
            vals[i] = s | ((d & BMASK) << 17);
            bks[i] = d >> BSHIFT;
            atomicAdd(&hist[bks[i]], 1);
        } else bks[i] = -1;
    }
    __syncthreads();

    int a0 = hist[2 * t], a1 = hist[2 * t + 1];
    int ts = a0 + a1;
    scanb[t] = ts;
    __syncthreads();
    for (int o = 1; o < 256; o <<= 1) {
        int u = (t >= o) ? scanb[t - o] : 0;
        __syncthreads();
        scanb[t] += u;
        __syncthreads();
    }
    int ex = scanb[t] - ts;
    lbase[2 * t] = ex;
    lbase[2 * t + 1] = ex + a0;
    __syncthreads();

    for (int b = t; b < NBUCK_MAX; b += 256) {
        int c = hist[b];
        int g = c ? atomicAdd(&gcur[b], c) : 0;
        gdelta[b] = g - lbase[b];
    }
#pragma unroll
    for (int i = 0; i < EPT; i++) {
        if (bks[i] >= 0) {
            int rr = atomicAdd(&cnt2[bks[i]], 1);
            int slot = lbase[bks[i]] + rr;
            stage[slot] = vals[i];
            sbucket[slot] = (unsigned short)bks[i];
        }
    }
    __syncthreads();
    for (int i = t; i < cntTile; i += 256) {
        int b = sbucket[i];
        binned[gdelta[b] + i] = stage[i];
    }
}

// Per-bucket: hist+scan -> rowptr, dinv; then placement -> csr.
__global__ void k_sortcsr(const int* __restrict__ bbase, const int* __restrict__ binned,
                          int* __restrict__ rowptr, float* __restrict__ dinv,
                          int* __restrict__ csr, int n, int E) {
    __shared__ int cnt[256];
    __shared__ int sc[256];
    __shared__ int rpl[256];
    __shared__ int lcur[256];
    int b = blockIdx.x, t = threadIdx.x;
    cnt[t] = 0; lcur[t] = 0;
    __syncthreads();
    int beg = bbase[b], end = bbase[b + 1];
    for (int i = beg + t; i < end; i += 256)
        atomicAdd(&cnt[(binned[i] >> 17) & BMASK], 1);
    __syncthreads();
    int v = cnt[t];
    sc[t] = v;
    __syncthreads();
    for (int o = 1; o < 256; o <<= 1) {
        int u = (t >= o) ? sc[t - o] : 0;
        __syncthreads();
        sc[t] += u;
        __syncthreads();
    }
    int rp = beg + sc[t] - v;
    rpl[t] = rp;
    int g = (b << BSHIFT) + t;
    if (g < n) {
        rowptr[g] = rp;
        dinv[g] = rsqrtf((float)v + 1.0f);
        if (g == n - 1) rowptr[n] = E;
    }
    __syncthreads();
    for (int i = beg + t; i < end; i += 256) {
        int vv = binned[i];
        int ln = (vv >> 17) & BMASK;
        int k = atomicAdd(&lcur[ln], 1);
        csr[rpl[ln] + k] = vv & 0x1FFFF;
    }
}

// hsb = pack_bf16((X @ W) * dinv[row]); block = 128 rows (2 rows/thread);
// wave w owns cols [w*M/4, (w+1)*M/4) -> each Ws float4 read is wave-uniform
// (LDS broadcast, conflict-free) and feeds 8 FMAs.
template<int K, int M>
__global__ __launch_bounds__(256) void k_gemm(const float* __restrict__ X,
                                              const float* __restrict__ W,
                                              const float* __restrict__ dinv,
                                              unsigned* __restrict__ hsb, int n) {
    constexpr int MW = M / 4;       // cols per wave
    __shared__ float Ws[K * M];
    for (int i = threadIdx.x; i < K * M; i += 256) Ws[i] = W[i];
    __syncthreads();
    int w = threadIdx.x >> 6, lane = threadIdx.x & 63;
    int wo = w * MW;
    int r0 = blockIdx.x * 128 + lane;
    float acc[2][MW];
#pragma unroll
    for (int i = 0; i < 2; i++)
#pragma unroll
        for (int j = 0; j < MW; j++) acc[i][j] = 0.f;

    for (int k = 0; k < K; k += 4) {
        float4 xv[2];
#pragma unroll
        for (int i = 0; i < 2; i++) {
            int rr = r0 + 64 * i;
            xv[i] = (rr < n) ? *(const float4*)(X + (size_t)rr * K + k)
                             : make_float4(0.f, 0.f, 0.f, 0.f);
        }
#pragma unroll
        for (int kk = 0; kk < 4; kk++) {
#pragma unroll
            for (int j = 0; j < MW; j += 4) {
                float4 wv = *(const float4*)&Ws[(k + kk) * M + wo + j];
#pragma unroll
                for (int i = 0; i < 2; i++) {
                    float xs = (kk == 0) ? xv[i].x : (kk == 1) ? xv[i].y
                             : (kk == 2) ? xv[i].z : xv[i].w;
                    acc[i][j + 0] += xs * wv.x;
                    acc[i][j + 1] += xs * wv.y;
                    acc[i][j + 2] += xs * wv.z;
                    acc[i][j + 3] += xs * wv.w;
                }
            }
        }
    }
#pragma unroll
    for (int i = 0; i < 2; i++) {
        int rr = r0 + 64 * i;
        if (rr < n) {
            float di = dinv[rr];
            unsigned p[MW / 2];
#pragma unroll
            for (int jj = 0; jj < MW / 2; jj++)
                p[jj] = pack_bf16(acc[i][2 * jj] * di, acc[i][2 * jj + 1] * di);
            unsigned* hr = hsb + (size_t)rr * (M / 2) + wo / 2;
#pragma unroll
            for (int jj = 0; jj < MW / 2; jj += 4)
                *(uint4*)(hr + jj) = make_uint4(p[jj], p[jj + 1], p[jj + 2], p[jj + 3]);
        }
    }
}

// Wave per node, F=64: 8 lanes/row (uint4 = 8 bf16 feats), 16 rows per load pair.
__global__ void k_agg64n(const int* __restrict__ rowptr, const int* __restrict__ csr,
                         const uint4* __restrict__ hsb, const float* __restrict__ dinv,
                         const float* __restrict__ bv, float* __restrict__ out, int n) {
    __shared__ float bs[64];
    if (threadIdx.x < 64) bs[threadIdx.x] = bv[threadIdx.x];
    __syncthreads();
    int d = (blockIdx.x * blockDim.x + threadIdx.x) >> 6;
    if (d >= n) return;
    int lane = threadIdx.x & 63;
    int q = lane >> 3;      // edge slot 0..7
    int r = lane & 7;       // feat chunk: feats 8r..8r+7
    int beg = rowptr[d], end = rowptr[d + 1];
    float acc[8];
#pragma unroll
    for (int i = 0; i < 8; i++) acc[i] = 0.f;
    int base = beg;
    for (; base + 16 <= end; base += 16) {
        int sA = csr[base + q];
        int sB = csr[base + 8 + q];
        uint4 wA = hsb[(size_t)sA * 8 + r];
        uint4 wB = hsb[(size_t)sB * 8 + r];
        acc[0] += __uint_as_float(wA.x << 16);  acc[1] += __uint_as_float(wA.x & 0xFFFF0000u);
        acc[2] += __uint_as_float(wA.y << 16);  acc[3] += __uint_as_float(wA.y & 0xFFFF0000u);
        acc[4] += __uint_as_float(wA.z << 16);  acc[5] += __uint_as_float(wA.z & 0xFFFF0000u);
        acc[6] += __uint_as_float(wA.w << 16);  acc[7] += __uint_as_float(wA.w & 0xFFFF0000u);
        acc[0] += __uint_as_float(wB.x << 16);  acc[1] += __uint_as_float(wB.x & 0xFFFF0000u);
        acc[2] += __uint_as_float(wB.y << 16);  acc[3] += __uint_as_float(wB.y & 0xFFFF0000u);
        acc[4] += __uint_as_float(wB.z << 16);  acc[5] += __uint_as_float(wB.z & 0xFFFF0000u);
        acc[6] += __uint_as_float(wB.w << 16);  acc[7] += __uint_as_float(wB.w & 0xFFFF0000u);
    }
    if (base + q < end) {
        uint4 w = hsb[(size_t)csr[base + q] * 8 + r];
        acc[0] += __uint_as_float(w.x << 16);  acc[1] += __uint_as_float(w.x & 0xFFFF0000u);
        acc[2] += __uint_as_float(w.y << 16);  acc[3] += __uint_as_float(w.y & 0xFFFF0000u);
        acc[4] += __uint_as_float(w.z << 16);  acc[5] += __uint_as_float(w.z & 0xFFFF0000u);
        acc[6] += __uint_as_float(w.w << 16);  acc[7] += __uint_as_float(w.w & 0xFFFF0000u);
    }
    if (base + 8 + q < end) {
        uint4 w = hsb[(size_t)csr[base + 8 + q] * 8 + r];
        acc[0] += __uint_as_float(w.x << 16);  acc[1] += __uint_as_float(w.x & 0xFFFF0000u);
        acc[2] += __uint_as_float(w.y << 16);  acc[3] += __uint_as_float(w.y & 0xFFFF0000u);
        acc[4] += __uint_as_float(w.z << 16);  acc[5] += __uint_as_float(w.z & 0xFFFF0000u);
        acc[6] += __uint_as_float(w.w << 16);  acc[7] += __uint_as_float(w.w & 0xFFFF0000u);
    }
#pragma unroll
    for (int i = 0; i < 8; i++) {
        acc[i] += __shfl_xor(acc[i], 8, 64);
        acc[i] += __shfl_xor(acc[i], 16, 64);
        acc[i] += __shfl_xor(acc[i], 32, 64);
    }
    uint4 ws = hsb[(size_t)d * 8 + r];
    acc[0] += __uint_as_float(ws.x << 16);  acc[1] += __uint_as_float(ws.x & 0xFFFF0000u);
    acc[2] += __uint_as_float(ws.y << 16);  acc[3] += __uint_as_float(ws.y & 0xFFFF0000u);
    acc[4] += __uint_as_float(ws.z << 16);  acc[5] += __uint_as_float(ws.z & 0xFFFF0000u);
    acc[6] += __uint_as_float(ws.w << 16);  acc[7] += __uint_as_float(ws.w & 0xFFFF0000u);
    if (q == 0) {
        float di = dinv[d];
        float v[8];
#pragma unroll
        for (int i = 0; i < 8; i++) v[i] = fmaxf(acc[i] * di + bs[8 * r + i], 0.f);
        float* o = out + (size_t)d * 64 + 8 * r;
        *(float4*)(o + 0) = make_float4(v[0], v[1], v[2], v[3]);
        *(float4*)(o + 4) = make_float4(v[4], v[5], v[6], v[7]);
    }
}

// Wave per node, F=32: 4 lanes/row, 32 rows per load pair.
__global__ void k_agg32n(const int* __restrict__ rowptr, const int* __restrict__ csr,
                         const uint4* __restrict__ hsb, const float* __restrict__ dinv,
                         const float* __restrict__ bv, float* __restrict__ out, int n) {
    __shared__ float bs[32];
    if (threadIdx.x < 32) bs[threadIdx.x] = bv[threadIdx.x];
    __syncthreads();
    int d = (blockIdx.x * blockDim.x + threadIdx.x) >> 6;
    if (d >= n) return;
    int lane = threadIdx.x & 63;
    int q = lane >> 2;      // edge slot 0..15
    int r = lane & 3;       // feat chunk: feats 8r..8r+7
    int beg = rowptr[d], end = rowptr[d + 1];
    float acc[8];
#pragma unroll
    for (int i = 0; i < 8; i++) acc[i] = 0.f;
    int base = beg;
    for (; base + 32 <= end; base += 32) {
        int sA = csr[base + q];
        int sB = csr[base + 16 + q];
        uint4 wA = hsb[(size_t)sA * 4 + r];
        uint4 wB = hsb[(size_t)sB * 4 + r];
        acc[0] += __uint_as_float(wA.x << 16);  acc[1] += __uint_as_float(wA.x & 0xFFFF0000u);
        acc[2] += __uint_as_float(wA.y << 16);  acc[3] += __uint_as_float(wA.y & 0xFFFF0000u);
        acc[4] += __uint_as_float(wA.z << 16);  acc[5] += __uint_as_float(wA.z & 0xFFFF0000u);
        acc[6] += __uint_as_float(wA.w << 16);  acc[7] += __uint_as_float(wA.w & 0xFFFF0000u);
        acc[0] += __uint_as_float(wB.x << 16);  acc[1] += __uint_as_float(wB.x & 0xFFFF0000u);
        acc[2] += __uint_as_float(wB.y << 16);  acc[3] += __uint_as_float(wB.y & 0xFFFF0000u);
        acc[4] += __uint_as_float(wB.z << 16);  acc[5] += __uint_as_float(wB.z & 0xFFFF0000u);
        acc[6] += __uint_as_float(wB.w << 16);  acc[7] += __uint_as_float(wB.w & 0xFFFF0000u);
    }
    if (base + q < end) {
        uint4 w = hsb[(size_t)csr[base + q] * 4 + r];
        acc[0] += __uint_as_float(w.x << 16);  acc[1] += __uint_as_float(w.x & 0xFFFF0000u);
        acc[2] += __uint_as_float(w.y << 16);  acc[3] += __uint_as_float(w.y & 0xFFFF0000u);
        acc[4] += __uint_as_float(w.z << 16);  acc[5] += __uint_as_float(w.z & 0xFFFF0000u);
        acc[6] += __uint_as_float(w.w << 16);  acc[7] += __uint_as_float(w.w & 0xFFFF0000u);
    }
    if (base + 16 + q < end) {
        uint4 w = hsb[(size_t)csr[base + 16 + q] * 4 + r];
        acc[0] += __uint_as_float(w.x << 16);  acc[1] += __uint_as_float(w.x & 0xFFFF0000u);
        acc[2] += __uint_as_float(w.y << 16);  acc[3] += __uint_as_float(w.y & 0xFFFF0000u);
        acc[4] += __uint_as_float(w.z << 16);  acc[5] += __uint_as_float(w.z & 0xFFFF0000u);
        acc[6] += __uint_as_float(w.w << 16);  acc[7] += __uint_as_float(w.w & 0xFFFF0000u);
    }
#pragma unroll
    for (int i = 0; i < 8; i++) {
        acc[i] += __shfl_xor(acc[i], 4, 64);
        acc[i] += __shfl_xor(acc[i], 8, 64);
        acc[i] += __shfl_xor(acc[i], 16, 64);
        acc[i] += __shfl_xor(acc[i], 32, 64);
    }
    uint4 ws = hsb[(size_t)d * 4 + r];
    acc[0] += __uint_as_float(ws.x << 16);  acc[1] += __uint_as_float(ws.x & 0xFFFF0000u);
    acc[2] += __uint_as_float(ws.y << 16);  acc[3] += __uint_as_float(ws.y & 0xFFFF0000u);
    acc[4] += __uint_as_float(ws.z << 16);  acc[5] += __uint_as_float(ws.z & 0xFFFF0000u);
    acc[6] += __uint_as_float(ws.w << 16);  acc[7] += __uint_as_float(ws.w & 0xFFFF0000u);
    if (q == 0) {
        float di = dinv[d];
        float v[8];
#pragma unroll
        for (int i = 0; i < 8; i++) v[i] = fmaxf(acc[i] * di + bs[8 * r + i], 0.f);
        float* o = out + (size_t)d * 32 + 8 * r;
        *(float4*)(o + 0) = make_float4(v[0], v[1], v[2], v[3]);
        *(float4*)(o + 4) = make_float4(v[4], v[5], v[6], v[7]);
    }
}

// logits = act2 @ Wc + bc; log_softmax
__global__ void k_classifier(const float* __restrict__ ACT, const float* __restrict__ Wc,
                             const float* __restrict__ bc, float* __restrict__ out, int n) {
    __shared__ float Wcs[32 * 10];
    __shared__ float bcs[10];
    for (int i = threadIdx.x; i < 320; i += blockDim.x) Wcs[i] = Wc[i];
    if (threadIdx.x < 10) bcs[threadIdx.x] = bc[threadIdx.x];
    __syncthreads();
    int r = blockIdx.x * blockDim.x + threadIdx.x;
    if (r >= n) return;
    const float* a = ACT + (size_t)r * 32;
    float logits[10];
#pragma unroll
    for (int c = 0; c < 10; c++) logits[c] = bcs[c];
#pragma unroll
    for (int k = 0; k < 32; k += 4) {
        float4 av = *(const float4*)(a + k);
#pragma unroll
        for (int c = 0; c < 10; c++) {
            logits[c] += av.x * Wcs[(k + 0) * 10 + c] + av.y * Wcs[(k + 1) * 10 + c]
                       + av.z * Wcs[(k + 2) * 10 + c] + av.w * Wcs[(k + 3) * 10 + c];
        }
    }
    float m = logits[0];
#pragma unroll
    for (int c = 1; c < 10; c++) m = fmaxf(m, logits[c]);
    float ssum = 0.f;
#pragma unroll
    for (int c = 0; c < 10; c++) ssum += __expf(logits[c] - m);
    float lse = m + __logf(ssum);
    float* o = out + (size_t)r * 10;
#pragma unroll
    for (int c = 0; c < 10; c++) o[c] = logits[c] - lse;
}

extern "C" void kernel_launch(void* const* d_in, const int* in_sizes, int n_in,
                              void* d_out, int out_size, void* d_ws, size_t ws_size,
                              hipStream_t stream) {
    const float* x  = (const float*)d_in[0];
    const int*   ei = (const int*)d_in[1];
    const float* W1 = (const float*)d_in[2];
    const float* b1 = (const float*)d_in[3];
    const float* W2 = (const float*)d_in[4];
    const float* b2 = (const float*)d_in[5];
    const float* Wc = (const float*)d_in[6];
    const float* bc = (const float*)d_in[7];
    float* out = (float*)d_out;

    const int N = in_sizes[0] / 128;
    const int E = in_sizes[1] / 2;
    const int* src = ei;
    const int* dst = ei + E;

    const int NBUCK = (N + BMASK) >> BSHIFT;   // <= 512
    const int NTILE = (E + TILE - 1) / TILE;

    char* ws = (char*)d_ws;
    size_t off = 0;
    auto alloc = [&](size_t elems) {
        void* p = ws + off;
        off += ((elems * 4 + 1023) & ~(size_t)1023);
        return p;
    };
    float*    dinv   = (float*)alloc(N);
    int*      bcnt   = (int*)alloc(NBUCK_MAX);
    int*      bbase  = (int*)alloc(NBUCK_MAX + 1);
    int*      gcur   = (int*)alloc(NBUCK_MAX);
    int*      rowptr = (int*)alloc(N + 1);
    int*      binned = (int*)alloc(E);
    int*      csr    = (int*)alloc(E);
    unsigned* hsb    = (unsigned*)alloc((size_t)N * 32);  // packed bf16 rows
    float*    act    = (float*)alloc((size_t)N * 64);     // act1 (N*64) then act2 (N*32)

    hipMemsetAsync(bcnt, 0, sizeof(int) * NBUCK_MAX, stream);

    // CSR build
    k_hist<<<512, 256, 0, stream>>>(dst, bcnt, E);
    k_scanb<<<1, NBUCK_MAX, 0, stream>>>(bcnt, bbase, gcur, E);
    k_binA<<<NTILE, 256, 0, stream>>>(src, dst, gcur, binned, E);
    k_sortcsr<<<NBUCK, 256, 0, stream>>>(bbase, binned, rowptr, dinv, csr, N, E);

    // Layer 1: 128 -> 64
    k_gemm<128, 64><<<(N + 127) / 128, 256, 0, stream>>>(x, W1, dinv, hsb, N);
    k_agg64n<<<(N * 64 + 255) / 256, 256, 0, stream>>>(rowptr, csr, (const uint4*)hsb,
                                                       dinv, b1, act, N);

    // Layer 2: 64 -> 32
    k_gemm<64, 32><<<(N + 127) / 128, 256, 0, stream>>>(act, W2, dinv, hsb, N);
    k_agg32n<<<(N * 64 + 255) / 256, 256, 0, stream>>>(rowptr, csr, (const uint4*)hsb,
                                                       dinv, b2, act, N);

    // Classifier + log_softmax
    k_classifier<<<(N + 255) / 256, 256, 0, stream>>>(act, Wc, bc, out, N);
}

// Round 9
// 366.545 us; speedup vs baseline: 1.3487x; 1.3487x over previous
//
#include <hip/hip_runtime.h>

// GCN pipeline (R9 = R6 with per-instantiation gemm row counts):
//   k_hist:    per-bucket(256 dst nodes) edge counts, LDS hist
//   k_scanb:   exclusive scan -> bbase[], gcur[]
//   k_binA:    tile-wise LDS counting sort by bucket -> binned[] (src|dstlo<<17)
//   k_sortcsr: per-bucket dstlo hist+scan -> rowptr, dinv; placement -> csr
//   k_gemm<K,M,R>: hsb = pack_bf16((X @ W) * dinv[row]); 64*R rows/block,
//              R rows/thread, wave-split cols; W in LDS (broadcast reads).
//              R chosen per-instantiation to avoid the compiler's full-hoist
//              spill (needs >32 independent float4 loads in the unrolled k-loop:
//              K/4*R > 32). gemm1: R=2 (782 blocks); gemm2: R=4 (known good).
//   k_agg64n/k_agg32n: wave-per-node uint4 bf16 gather (8/16 rows per load instr)
//   k_classifier: 32->10 + log_softmax

#define BSHIFT 8
#define BMASK 255
#define NBUCK_MAX 512
#define TILE 4096
#define EPT 16             // TILE / 256

__device__ __forceinline__ unsigned pack_bf16(float lo, float hi) {
    unsigned ul = __float_as_uint(lo);
    ul = (ul + 0x7FFFu + ((ul >> 16) & 1u)) >> 16;
    unsigned uh = __float_as_uint(hi);
    uh = ((uh + 0x7FFFu + ((uh >> 16) & 1u)) >> 16) << 16;
    return ul | uh;
}

__global__ void k_hist(const int* __restrict__ dst, int* __restrict__ bcnt, int E) {
    __shared__ int h[NBUCK_MAX];
    for (int i = threadIdx.x; i < NBUCK_MAX; i += blockDim.x) h[i] = 0;
    __syncthreads();
    for (int e = blockIdx.x * blockDim.x + threadIdx.x; e < E; e += gridDim.x * blockDim.x)
        atomicAdd(&h[dst[e] >> BSHIFT], 1);
    __syncthreads();
    for (int i = threadIdx.x; i < NBUCK_MAX; i += blockDim.x)
        if (h[i]) atomicAdd(&bcnt[i], h[i]);
}

__global__ void k_scanb(const int* __restrict__ bcnt, int* __restrict__ bbase,
                        int* __restrict__ gcur, int E) {
    __shared__ int s[NBUCK_MAX];
    int t = threadIdx.x;
    int v = bcnt[t];
    s[t] = v;
    __syncthreads();
    for (int o = 1; o < NBUCK_MAX; o <<= 1) {
        int u = (t >= o) ? s[t - o] : 0;
        __syncthreads();
        s[t] += u;
        __syncthreads();
    }
    int ex = s[t] - v;
    bbase[t] = ex;
    gcur[t] = ex;
    if (t == NBUCK_MAX - 1) bbase[NBUCK_MAX] = E;
}

// Tile-wise LDS counting sort by bucket; dump contiguous per-bucket runs.
__global__ __launch_bounds__(256) void k_binA(const int* __restrict__ src,
                                              const int* __restrict__ dst,
                                              int* __restrict__ gcur,
                                              int* __restrict__ binned, int E) {
    __shared__ int hist[NBUCK_MAX];
    __shared__ int lbase[NBUCK_MAX];
    __shared__ int gdelta[NBUCK_MAX];
    __shared__ int cnt2[NBUCK_MAX];
    __shared__ int scanb[256];
    __shared__ int stage[TILE];
    __shared__ unsigned short sbucket[TILE];

    int t = threadIdx.x;
    for (int i = t; i < NBUCK_MAX; i += 256) { hist[i] = 0; cnt2[i] = 0; }
    __syncthreads();

    int tileStart = blockIdx.x * TILE;
    int cntTile = min(TILE, E - tileStart);

    int vals[EPT];
    int bks[EPT];
#pragma unroll
    for (int i = 0; i < EPT; i++) {
        int e = tileStart + t + i * 256;
        if (e < E) {
            int s = src[e], d = dst[e];
            vals[i] = s | ((d & BMASK) << 17);
            bks[i] = d >> BSHIFT;
            atomicAdd(&hist[bks[i]], 1);
        } else bks[i] = -1;
    }
    __syncthreads();

    int a0 = hist[2 * t], a1 = hist[2 * t + 1];
    int ts = a0 + a1;
    scanb[t] = ts;
    __syncthreads();
    for (int o = 1; o < 256; o <<= 1) {
        int u = (t >= o) ? scanb[t - o] : 0;
        __syncthreads();
        scanb[t] += u;
        __syncthreads();
    }
    int ex = scanb[t] - ts;
    lbase[2 * t] = ex;
    lbase[2 * t + 1] = ex + a0;
    __syncthreads();

    for (int b = t; b < NBUCK_MAX; b += 256) {
        int c = hist[b];
        int g = c ? atomicAdd(&gcur[b], c) : 0;
        gdelta[b] = g - lbase[b];
    }
#pragma unroll
    for (int i = 0; i < EPT; i++) {
        if (bks[i] >= 0) {
            int rr = atomicAdd(&cnt2[bks[i]], 1);
            int slot = lbase[bks[i]] + rr;
            stage[slot] = vals[i];
            sbucket[slot] = (unsigned short)bks[i];
        }
    }
    __syncthreads();
    for (int i = t; i < cntTile; i += 256) {
        int b = sbucket[i];
        binned[gdelta[b] + i] = stage[i];
    }
}

// Per-bucket: hist+scan -> rowptr, dinv; then placement -> csr.
__global__ void k_sortcsr(const int* __restrict__ bbase, const int* __restrict__ binned,
                          int* __restrict__ rowptr, float* __restrict__ dinv,
                          int* __restrict__ csr, int n, int E) {
    __shared__ int cnt[256];
    __shared__ int sc[256];
    __shared__ int rpl[256];
    __shared__ int lcur[256];
    int b = blockIdx.x, t = threadIdx.x;
    cnt[t] = 0; lcur[t] = 0;
    __syncthreads();
    int beg = bbase[b], end = bbase[b + 1];
    for (int i = beg + t; i < end; i += 256)
        atomicAdd(&cnt[(binned[i] >> 17) & BMASK], 1);
    __syncthreads();
    int v = cnt[t];
    sc[t] = v;
    __syncthreads();
    for (int o = 1; o < 256; o <<= 1) {
        int u = (t >= o) ? sc[t - o] : 0;
        __syncthreads();
        sc[t] += u;
        __syncthreads();
    }
    int rp = beg + sc[t] - v;
    rpl[t] = rp;
    int g = (b << BSHIFT) + t;
    if (g < n) {
        rowptr[g] = rp;
        dinv[g] = rsqrtf((float)v + 1.0f);
        if (g == n - 1) rowptr[n] = E;
    }
    __syncthreads();
    for (int i = beg + t; i < end; i += 256) {
        int vv = binned[i];
        int ln = (vv >> 17) & BMASK;
        int k = atomicAdd(&lcur[ln], 1);
        csr[rpl[ln] + k] = vv & 0x1FFFF;
    }
}

// hsb = pack_bf16((X @ W) * dinv[row]); block = 64*R rows (R rows/thread);
// wave w owns cols [w*M/4, (w+1)*M/4): Ws float4 reads are wave-uniform
// (LDS broadcast, conflict-free).
template<int K, int M, int R>
__global__ __launch_bounds__(256) void k_gemm(const float* __restrict__ X,
                                              const float* __restrict__ W,
                                              const float* __restrict__ dinv,
                                              unsigned* __restrict__ hsb, int n) {
    constexpr int MW = M / 4;       // cols per wave
    __shared__ float Ws[K * M];
    for (int i = threadIdx.x; i < K * M; i += 256) Ws[i] = W[i];
    __syncthreads();
    int w = threadIdx.x >> 6, lane = threadIdx.x & 63;
    int wo = w * MW;
    int r0 = blockIdx.x * (64 * R) + lane;
    float acc[R][MW];
#pragma unroll
    for (int i = 0; i < R; i++)
#pragma unroll
        for (int j = 0; j < MW; j++) acc[i][j] = 0.f;

    for (int k = 0; k < K; k += 4) {
        float4 xv[R];
#pragma unroll
        for (int i = 0; i < R; i++) {
            int rr = r0 + 64 * i;
            xv[i] = (rr < n) ? *(const float4*)(X + (size_t)rr * K + k)
                             : make_float4(0.f, 0.f, 0.f, 0.f);
        }
#pragma unroll
        for (int kk = 0; kk < 4; kk++) {
#pragma unroll
            for (int j = 0; j < MW; j += 4) {
                float4 wv = *(const float4*)&Ws[(k + kk) * M + wo + j];
#pragma unroll
                for (int i = 0; i < R; i++) {
                    float xs = (kk == 0) ? xv[i].x : (kk == 1) ? xv[i].y
                             : (kk == 2) ? xv[i].z : xv[i].w;
                    acc[i][j + 0] += xs * wv.x;
                    acc[i][j + 1] += xs * wv.y;
                    acc[i][j + 2] += xs * wv.z;
                    acc[i][j + 3] += xs * wv.w;
                }
            }
        }
    }
#pragma unroll
    for (int i = 0; i < R; i++) {
        int rr = r0 + 64 * i;
        if (rr < n) {
            float di = dinv[rr];
            unsigned p[MW / 2];
#pragma unroll
            for (int jj = 0; jj < MW / 2; jj++)
                p[jj] = pack_bf16(acc[i][2 * jj] * di, acc[i][2 * jj + 1] * di);
            unsigned* hr = hsb + (size_t)rr * (M / 2) + wo / 2;
#pragma unroll
            for (int jj = 0; jj < MW / 2; jj += 4)
                *(uint4*)(hr + jj) = make_uint4(p[jj], p[jj + 1], p[jj + 2], p[jj + 3]);
        }
    }
}

// Wave per node, F=64: 8 lanes/row (uint4 = 8 bf16 feats), 16 rows per load pair.
__global__ void k_agg64n(const int* __restrict__ rowptr, const int* __restrict__ csr,
                         const uint4* __restrict__ hsb, const float* __restrict__ dinv,
                         const float* __restrict__ bv, float* __restrict__ out, int n) {
    __shared__ float bs[64];
    if (threadIdx.x < 64) bs[threadIdx.x] = bv[threadIdx.x];
    __syncthreads();
    int d = (blockIdx.x * blockDim.x + threadIdx.x) >> 6;
    if (d >= n) return;
    int lane = threadIdx.x & 63;
    int q = lane >> 3;      // edge slot 0..7
    int r = lane & 7;       // feat chunk: feats 8r..8r+7
    int beg = rowptr[d], end = rowptr[d + 1];
    float acc[8];
#pragma unroll
    for (int i = 0; i < 8; i++) acc[i] = 0.f;
    int base = beg;
    for (; base + 16 <= end; base += 16) {
        int sA = csr[base + q];
        int sB = csr[base + 8 + q];
        uint4 wA = hsb[(size_t)sA * 8 + r];
        uint4 wB = hsb[(size_t)sB * 8 + r];
        acc[0] += __uint_as_float(wA.x << 16);  acc[1] += __uint_as_float(wA.x & 0xFFFF0000u);
        acc[2] += __uint_as_float(wA.y << 16);  acc[3] += __uint_as_float(wA.y & 0xFFFF0000u);
        acc[4] += __uint_as_float(wA.z << 16);  acc[5] += __uint_as_float(wA.z & 0xFFFF0000u);
        acc[6] += __uint_as_float(wA.w << 16);  acc[7] += __uint_as_float(wA.w & 0xFFFF0000u);
        acc[0] += __uint_as_float(wB.x << 16);  acc[1] += __uint_as_float(wB.x & 0xFFFF0000u);
        acc[2] += __uint_as_float(wB.y << 16);  acc[3] += __uint_as_float(wB.y & 0xFFFF0000u);
        acc[4] += __uint_as_float(wB.z << 16);  acc[5] += __uint_as_float(wB.z & 0xFFFF0000u);
        acc[6] += __uint_as_float(wB.w << 16);  acc[7] += __uint_as_float(wB.w & 0xFFFF0000u);
    }
    if (base + q < end) {
        uint4 w = hsb[(size_t)csr[base + q] * 8 + r];
        acc[0] += __uint_as_float(w.x << 16);  acc[1] += __uint_as_float(w.x & 0xFFFF0000u);
        acc[2] += __uint_as_float(w.y << 16);  acc[3] += __uint_as_float(w.y & 0xFFFF0000u);
        acc[4] += __uint_as_float(w.z << 16);  acc[5] += __uint_as_float(w.z & 0xFFFF0000u);
        acc[6] += __uint_as_float(w.w << 16);  acc[7] += __uint_as_float(w.w & 0xFFFF0000u);
    }
    if (base + 8 + q < end) {
        uint4 w = hsb[(size_t)csr[base + 8 + q] * 8 + r];
        acc[0] += __uint_as_float(w.x << 16);  acc[1] += __uint_as_float(w.x & 0xFFFF0000u);
        acc[2] += __uint_as_float(w.y << 16);  acc[3] += __uint_as_float(w.y & 0xFFFF0000u);
        acc[4] += __uint_as_float(w.z << 16);  acc[5] += __uint_as_float(w.z & 0xFFFF0000u);
        acc[6] += __uint_as_float(w.w << 16);  acc[7] += __uint_as_float(w.w & 0xFFFF0000u);
    }
#pragma unroll
    for (int i = 0; i < 8; i++) {
        acc[i] += __shfl_xor(acc[i], 8, 64);
        acc[i] += __shfl_xor(acc[i], 16, 64);
        acc[i] += __shfl_xor(acc[i], 32, 64);
    }
    uint4 ws = hsb[(size_t)d * 8 + r];
    acc[0] += __uint_as_float(ws.x << 16);  acc[1] += __uint_as_float(ws.x & 0xFFFF0000u);
    acc[2] += __uint_as_float(ws.y << 16);  acc[3] += __uint_as_float(ws.y & 0xFFFF0000u);
    acc[4] += __uint_as_float(ws.z << 16);  acc[5] += __uint_as_float(ws.z & 0xFFFF0000u);
    acc[6] += __uint_as_float(ws.w << 16);  acc[7] += __uint_as_float(ws.w & 0xFFFF0000u);
    if (q == 0) {
        float di = dinv[d];
        float v[8];
#pragma unroll
        for (int i = 0; i < 8; i++) v[i] = fmaxf(acc[i] * di + bs[8 * r + i], 0.f);
        float* o = out + (size_t)d * 64 + 8 * r;
        *(float4*)(o + 0) = make_float4(v[0], v[1], v[2], v[3]);
        *(float4*)(o + 4) = make_float4(v[4], v[5], v[6], v[7]);
    }
}

// Wave per node, F=32: 4 lanes/row, 32 rows per load pair.
__global__ void k_agg32n(const int* __restrict__ rowptr, const int* __restrict__ csr,
                         const uint4* __restrict__ hsb, const float* __restrict__ dinv,
                         const float* __restrict__ bv, float* __restrict__ out, int n) {
    __shared__ float bs[32];
    if (threadIdx.x < 32) bs[threadIdx.x] = bv[threadIdx.x];
    __syncthreads();
    int d = (blockIdx.x * blockDim.x + threadIdx.x) >> 6;
    if (d >= n) return;
    int lane = threadIdx.x & 63;
    int q = lane >> 2;      // edge slot 0..15
    int r = lane & 3;       // feat chunk: feats 8r..8r+7
    int beg = rowptr[d], end = rowptr[d + 1];
    float acc[8];
#pragma unroll
    for (int i = 0; i < 8; i++) acc[i] = 0.f;
    int base = beg;
    for (; base + 32 <= end; base += 32) {
        int sA = csr[base + q];
        int sB = csr[base + 16 + q];
        uint4 wA = hsb[(size_t)sA * 4 + r];
        uint4 wB = hsb[(size_t)sB * 4 + r];
        acc[0] += __uint_as_float(wA.x << 16);  acc[1] += __uint_as_float(wA.x & 0xFFFF0000u);
        acc[2] += __uint_as_float(wA.y << 16);  acc[3] += __uint_as_float(wA.y & 0xFFFF0000u);
        acc[4] += __uint_as_float(wA.z << 16);  acc[5] += __uint_as_float(wA.z & 0xFFFF0000u);
        acc[6] += __uint_as_float(wA.w << 16);  acc[7] += __uint_as_float(wA.w & 0xFFFF0000u);
        acc[0] += __uint_as_float(wB.x << 16);  acc[1] += __uint_as_float(wB.x & 0xFFFF0000u);
        acc[2] += __uint_as_float(wB.y << 16);  acc[3] += __uint_as_float(wB.y & 0xFFFF0000u);
        acc[4] += __uint_as_float(wB.z << 16);  acc[5] += __uint_as_float(wB.z & 0xFFFF0000u);
        acc[6] += __uint_as_float(wB.w << 16);  acc[7] += __uint_as_float(wB.w & 0xFFFF0000u);
    }
    if (base + q < end) {
        uint4 w = hsb[(size_t)csr[base + q] * 4 + r];
        acc[0] += __uint_as_float(w.x << 16);  acc[1] += __uint_as_float(w.x & 0xFFFF0000u);
        acc[2] += __uint_as_float(w.y << 16);  acc[3] += __uint_as_float(w.y & 0xFFFF0000u);
        acc[4] += __uint_as_float(w.z << 16);  acc[5] += __uint_as_float(w.z & 0xFFFF0000u);
        acc[6] += __uint_as_float(w.w << 16);  acc[7] += __uint_as_float(w.w & 0xFFFF0000u);
    }
    if (base + 16 + q < end) {
        uint4 w = hsb[(size_t)csr[base + 16 + q] * 4 + r];
        acc[0] += __uint_as_float(w.x << 16);  acc[1] += __uint_as_float(w.x & 0xFFFF0000u);
        acc[2] += __uint_as_float(w.y << 16);  acc[3] += __uint_as_float(w.y & 0xFFFF0000u);
        acc[4] += __uint_as_float(w.z << 16);  acc[5] += __uint_as_float(w.z & 0xFFFF0000u);
        acc[6] += __uint_as_float(w.w << 16);  acc[7] += __uint_as_float(w.w & 0xFFFF0000u);
    }
#pragma unroll
    for (int i = 0; i < 8; i++) {
        acc[i] += __shfl_xor(acc[i], 4, 64);
        acc[i] += __shfl_xor(acc[i], 8, 64);
        acc[i] += __shfl_xor(acc[i], 16, 64);
        acc[i] += __shfl_xor(acc[i], 32, 64);
    }
    uint4 ws = hsb[(size_t)d * 4 + r];
    acc[0] += __uint_as_float(ws.x << 16);  acc[1] += __uint_as_float(ws.x & 0xFFFF0000u);
    acc[2] += __uint_as_float(ws.y << 16);  acc[3] += __uint_as_float(ws.y & 0xFFFF0000u);
    acc[4] += __uint_as_float(ws.z << 16);  acc[5] += __uint_as_float(ws.z & 0xFFFF0000u);
    acc[6] += __uint_as_float(ws.w << 16);  acc[7] += __uint_as_float(ws.w & 0xFFFF0000u);
    if (q == 0) {
        float di = dinv[d];
        float v[8];
#pragma unroll
        for (int i = 0; i < 8; i++) v[i] = fmaxf(acc[i] * di + bs[8 * r + i], 0.f);
        float* o = out + (size_t)d * 32 + 8 * r;
        *(float4*)(o + 0) = make_float4(v[0], v[1], v[2], v[3]);
        *(float4*)(o + 4) = make_float4(v[4], v[5], v[6], v[7]);
    }
}

// logits = act2 @ Wc + bc; log_softmax
__global__ void k_classifier(const float* __restrict__ ACT, const float* __restrict__ Wc,
                             const float* __restrict__ bc, float* __restrict__ out, int n) {
    __shared__ float Wcs[32 * 10];
    __shared__ float bcs[10];
    for (int i = threadIdx.x; i < 320; i += blockDim.x) Wcs[i] = Wc[i];
    if (threadIdx.x < 10) bcs[threadIdx.x] = bc[threadIdx.x];
    __syncthreads();
    int r = blockIdx.x * blockDim.x + threadIdx.x;
    if (r >= n) return;
    const float* a = ACT + (size_t)r * 32;
    float logits[10];
#pragma unroll
    for (int c = 0; c < 10; c++) logits[c] = bcs[c];
#pragma unroll
    for (int k = 0; k < 32; k += 4) {
        float4 av = *(const float4*)(a + k);
#pragma unroll
        for (int c = 0; c < 10; c++) {
            logits[c] += av.x * Wcs[(k + 0) * 10 + c] + av.y * Wcs[(k + 1) * 10 + c]
                       + av.z * Wcs[(k + 2) * 10 + c] + av.w * Wcs[(k + 3) * 10 + c];
        }
    }
    float m = logits[0];
#pragma unroll
    for (int c = 1; c < 10; c++) m = fmaxf(m, logits[c]);
    float ssum = 0.f;
#pragma unroll
    for (int c = 0; c < 10; c++) ssum += __expf(logits[c] - m);
    float lse = m + __logf(ssum);
    float* o = out + (size_t)r * 10;
#pragma unroll
    for (int c = 0; c < 10; c++) o[c] = logits[c] - lse;
}

extern "C" void kernel_launch(void* const* d_in, const int* in_sizes, int n_in,
                              void* d_out, int out_size, void* d_ws, size_t ws_size,
                              hipStream_t stream) {
    const float* x  = (const float*)d_in[0];
    const int*   ei = (const int*)d_in[1];
    const float* W1 = (const float*)d_in[2];
    const float* b1 = (const float*)d_in[3];
    const float* W2 = (const float*)d_in[4];
    const float* b2 = (const float*)d_in[5];
    const float* Wc = (const float*)d_in[6];
    const float* bc = (const float*)d_in[7];
    float* out = (float*)d_out;

    const int N = in_sizes[0] / 128;
    const int E = in_sizes[1] / 2;
    const int* src = ei;
    const int* dst = ei + E;

    const int NBUCK = (N + BMASK) >> BSHIFT;   // <= 512
    const int NTILE = (E + TILE - 1) / TILE;

    char* ws = (char*)d_ws;
    size_t off = 0;
    auto alloc = [&](size_t elems) {
        void* p = ws + off;
        off += ((elems * 4 + 1023) & ~(size_t)1023);
        return p;
    };
    float*    dinv   = (float*)alloc(N);
    int*      bcnt   = (int*)alloc(NBUCK_MAX);
    int*      bbase  = (int*)alloc(NBUCK_MAX + 1);
    int*      gcur   = (int*)alloc(NBUCK_MAX);
    int*      rowptr = (int*)alloc(N + 1);
    int*      binned = (int*)alloc(E);
    int*      csr    = (int*)alloc(E);
    unsigned* hsb    = (unsigned*)alloc((size_t)N * 32);  // packed bf16 rows
    float*    act    = (float*)alloc((size_t)N * 64);     // act1 (N*64) then act2 (N*32)

    hipMemsetAsync(bcnt, 0, sizeof(int) * NBUCK_MAX, stream);

    // CSR build
    k_hist<<<512, 256, 0, stream>>>(dst, bcnt, E);
    k_scanb<<<1, NBUCK_MAX, 0, stream>>>(bcnt, bbase, gcur, E);
    k_binA<<<NTILE, 256, 0, stream>>>(src, dst, gcur, binned, E);
    k_sortcsr<<<NBUCK, 256, 0, stream>>>(bbase, binned, rowptr, dinv, csr, N, E);

    // Layer 1: 128 -> 64  (R=2: 128 rows/block, 782 blocks)
    k_gemm<128, 64, 2><<<(N + 127) / 128, 256, 0, stream>>>(x, W1, dinv, hsb, N);
    k_agg64n<<<(N * 64 + 255) / 256, 256, 0, stream>>>(rowptr, csr, (const uint4*)hsb,
                                                       dinv, b1, act, N);

    // Layer 2: 64 -> 32  (R=4: 256 rows/block — the known-good R6 shape)
    k_gemm<64, 32, 4><<<(N + 255) / 256, 256, 0, stream>>>(act, W2, dinv, hsb, N);
    k_agg32n<<<(N * 64 + 255) / 256, 256, 0, stream>>>(rowptr, csr, (const uint4*)hsb,
                                                       dinv, b2, act, N);

    // Classifier + log_softmax
    k_classifier<<<(N + 255) / 256, 256, 0, stream>>>(act, Wc, bc, out, N);
}

// Round 11
// 362.969 us; speedup vs baseline: 1.3620x; 1.0099x over previous
//
#include <hip/hip_runtime.h>

// GCN pipeline (R11 = R10 with macro fix):
//   k_hist:    per-bucket(256 dst nodes) edge counts, LDS hist
//   k_scanb:   exclusive scan -> bbase[], gcur[]
//   k_binA:    tile-wise LDS counting sort by bucket -> binned[] (src|dstlo<<17)
//   k_sortcsr: per-bucket dstlo hist+scan -> rowptr, dinv; placement -> csr
//   k_gemm<K,M,R>: hsb = pack_bf16((X @ W) * dinv[row])
//   k_agg64f:  wave-per-node bf16 gather + relu + in-register 64x32 gemm (W2 in
//              regs, shfl reduce) -> hsb2 (bf16). act1 never materialized.
//   k_agg32f:  wave-per-node bf16 gather + relu + in-register 32x10 classifier
//              + log_softmax -> out. act2 never materialized.

#define BSHIFT 8
#define BMASK 255
#define NBUCK_MAX 512
#define TILE 4096
#define EPT 16             // TILE / 256
#define NPW 4              // nodes per wave in fused agg kernels

__device__ __forceinline__ unsigned pack_bf16(float lo, float hi) {
    unsigned ul = __float_as_uint(lo);
    ul = (ul + 0x7FFFu + ((ul >> 16) & 1u)) >> 16;
    unsigned uh = __float_as_uint(hi);
    uh = ((uh + 0x7FFFu + ((uh >> 16) & 1u)) >> 16) << 16;
    return ul | uh;
}

__global__ void k_hist(const int* __restrict__ dst, int* __restrict__ bcnt, int E) {
    __shared__ int h[NBUCK_MAX];
    for (int i = threadIdx.x; i < NBUCK_MAX; i += blockDim.x) h[i] = 0;
    __syncthreads();
    for (int e = blockIdx.x * blockDim.x + threadIdx.x; e < E; e += gridDim.x * blockDim.x)
        atomicAdd(&h[dst[e] >> BSHIFT], 1);
    __syncthreads();
    for (int i = threadIdx.x; i < NBUCK_MAX; i += blockDim.x)
        if (h[i]) atomicAdd(&bcnt[i], h[i]);
}

__global__ void k_scanb(const int* __restrict__ bcnt, int* __restrict__ bbase,
                        int* __restrict__ gcur, int E) {
    __shared__ int s[NBUCK_MAX];
    int t = threadIdx.x;
    int v = bcnt[t];
    s[t] = v;
    __syncthreads();
    for (int o = 1; o < NBUCK_MAX; o <<= 1) {
        int u = (t >= o) ? s[t - o] : 0;
        __syncthreads();
        s[t] += u;
        __syncthreads();
    }
    int ex = s[t] - v;
    bbase[t] = ex;
    gcur[t] = ex;
    if (t == NBUCK_MAX - 1) bbase[NBUCK_MAX] = E;
}

// Tile-wise LDS counting sort by bucket; dump contiguous per-bucket runs.
__global__ __launch_bounds__(256) void k_binA(const int* __restrict__ src,
                                              const int* __restrict__ dst,
                                              int* __restrict__ gcur,
                                              int* __restrict__ binned, int E) {
    __shared__ int hist[NBUCK_MAX];
    __shared__ int lbase[NBUCK_MAX];
    __shared__ int gdelta[NBUCK_MAX];
    __shared__ int cnt2[NBUCK_MAX];
    __shared__ int scanb[256];
    __shared__ int stage[TILE];
    __shared__ unsigned short sbucket[TILE];

    int t = threadIdx.x;
    for (int i = t; i < NBUCK_MAX; i += 256) { hist[i] = 0; cnt2[i] = 0; }
    __syncthreads();

    int tileStart = blockIdx.x * TILE;
    int cntTile = min(TILE, E - tileStart);

    int vals[EPT];
    int bks[EPT];
#pragma unroll
    for (int i = 0; i < EPT; i++) {
        int e = tileStart + t + i * 256;
        if (e < E) {
            int s = src[e], d = dst[e];
            vals[i] = s | ((d & BMASK) << 17);
            bks[i] = d >> BSHIFT;
            atomicAdd(&hist[bks[i]], 1);
        } else bks[i] = -1;
    }
    __syncthreads();

    int a0 = hist[2 * t], a1 = hist[2 * t + 1];
    int ts = a0 + a1;
    scanb[t] = ts;
    __syncthreads();
    for (int o = 1; o < 256; o <<= 1) {
        int u = (t >= o) ? scanb[t - o] : 0;
        __syncthreads();
        scanb[t] += u;
        __syncthreads();
    }
    int ex = scanb[t] - ts;
    lbase[2 * t] = ex;
    lbase[2 * t + 1] = ex + a0;
    __syncthreads();

    for (int b = t; b < NBUCK_MAX; b += 256) {
        int c = hist[b];
        int g = c ? atomicAdd(&gcur[b], c) : 0;
        gdelta[b] = g - lbase[b];
    }
#pragma unroll
    for (int i = 0; i < EPT; i++) {
        if (bks[i] >= 0) {
            int rr = atomicAdd(&cnt2[bks[i]], 1);
            int slot = lbase[bks[i]] + rr;
            stage[slot] = vals[i];
            sbucket[slot] = (unsigned short)bks[i];
        }
    }
    __syncthreads();
    for (int i = t; i < cntTile; i += 256) {
        int b = sbucket[i];
        binned[gdelta[b] + i] = stage[i];
    }
}

// Per-bucket: hist+scan -> rowptr, dinv; then placement -> csr.
__global__ void k_sortcsr(const int* __restrict__ bbase, const int* __restrict__ binned,
                          int* __restrict__ rowptr, float* __restrict__ dinv,
                          int* __restrict__ csr, int n, int E) {
    __shared__ int cnt[256];
    __shared__ int sc[256];
    __shared__ int rpl[256];
    __shared__ int lcur[256];
    int b = blockIdx.x, t = threadIdx.x;
    cnt[t] = 0; lcur[t] = 0;
    __syncthreads();
    int beg = bbase[b], end = bbase[b + 1];
    for (int i = beg + t; i < end; i += 256)
        atomicAdd(&cnt[(binned[i] >> 17) & BMASK], 1);
    __syncthreads();
    int v = cnt[t];
    sc[t] = v;
    __syncthreads();
    for (int o = 1; o < 256; o <<= 1) {
        int u = (t >= o) ? sc[t - o] : 0;
        __syncthreads();
        sc[t] += u;
        __syncthreads();
    }
    int rp = beg + sc[t] - v;
    rpl[t] = rp;
    int g = (b << BSHIFT) + t;
    if (g < n) {
        rowptr[g] = rp;
        dinv[g] = rsqrtf((float)v + 1.0f);
        if (g == n - 1) rowptr[n] = E;
    }
    __syncthreads();
    for (int i = beg + t; i < end; i += 256) {
        int vv = binned[i];
        int ln = (vv >> 17) & BMASK;
        int k = atomicAdd(&lcur[ln], 1);
        csr[rpl[ln] + k] = vv & 0x1FFFF;
    }
}

// hsb = pack_bf16((X @ W) * dinv[row]); block = 64*R rows (R rows/thread);
// wave w owns cols [w*M/4, (w+1)*M/4): Ws float4 reads are wave-uniform
// (LDS broadcast, conflict-free). R chosen so the unrolled k-loop has >32
// independent float4 loads (K/4*R > 32) to avoid full-hoist spill.
template<int K, int M, int R>
__global__ __launch_bounds__(256) void k_gemm(const float* __restrict__ X,
                                              const float* __restrict__ W,
                                              const float* __restrict__ dinv,
                                              unsigned* __restrict__ hsb, int n) {
    constexpr int MW = M / 4;       // cols per wave
    __shared__ float Ws[K * M];
    for (int i = threadIdx.x; i < K * M; i += 256) Ws[i] = W[i];
    __syncthreads();
    int w = threadIdx.x >> 6, lane = threadIdx.x & 63;
    int wo = w * MW;
    int r0 = blockIdx.x * (64 * R) + lane;
    float acc[R][MW];
#pragma unroll
    for (int i = 0; i < R; i++)
#pragma unroll
        for (int j = 0; j < MW; j++) acc[i][j] = 0.f;

    for (int k = 0; k < K; k += 4) {
        float4 xv[R];
#pragma unroll
        for (int i = 0; i < R; i++) {
            int rr = r0 + 64 * i;
            xv[i] = (rr < n) ? *(const float4*)(X + (size_t)rr * K + k)
                             : make_float4(0.f, 0.f, 0.f, 0.f);
        }
#pragma unroll
        for (int kk = 0; kk < 4; kk++) {
#pragma unroll
            for (int j = 0; j < MW; j += 4) {
                float4 wv = *(const float4*)&Ws[(k + kk) * M + wo + j];
#pragma unroll
                for (int i = 0; i < R; i++) {
                    float xs = (kk == 0) ? xv[i].x : (kk == 1) ? xv[i].y
                             : (kk == 2) ? xv[i].z : xv[i].w;
                    acc[i][j + 0] += xs * wv.x;
                    acc[i][j + 1] += xs * wv.y;
                    acc[i][j + 2] += xs * wv.z;
                    acc[i][j + 3] += xs * wv.w;
                }
            }
        }
    }
#pragma unroll
    for (int i = 0; i < R; i++) {
        int rr = r0 + 64 * i;
        if (rr < n) {
            float di = dinv[rr];
            unsigned p[MW / 2];
#pragma unroll
            for (int jj = 0; jj < MW / 2; jj++)
                p[jj] = pack_bf16(acc[i][2 * jj] * di, acc[i][2 * jj + 1] * di);
            unsigned* hr = hsb + (size_t)rr * (M / 2) + wo / 2;
#pragma unroll
            for (int jj = 0; jj < MW / 2; jj += 4)
                *(uint4*)(hr + jj) = make_uint4(p[jj], p[jj + 1], p[jj + 2], p[jj + 3]);
        }
    }
}

#define ACC8(V) \
    acc[0] += __uint_as_float((V).x << 16);  acc[1] += __uint_as_float((V).x & 0xFFFF0000u); \
    acc[2] += __uint_as_float((V).y << 16);  acc[3] += __uint_as_float((V).y & 0xFFFF0000u); \
    acc[4] += __uint_as_float((V).z << 16);  acc[5] += __uint_as_float((V).z & 0xFFFF0000u); \
    acc[6] += __uint_as_float((V).w << 16);  acc[7] += __uint_as_float((V).w & 0xFFFF0000u);

// Fused layer-1 aggregate + relu + 64x32 gemm + bf16 pack -> hsb2.
// Wave per node-group (NPW nodes). Lane (q=lane>>3, r=lane&7).
// Gather: 8 lanes/row (uint4 = 8 bf16 feats), edge slot q.
// After xor-8/16/32 reduce, all lanes hold feats 8r..8r+7 of the summed row.
// Lane computes h2[4q..4q+3] partial from its chunk; xor-1/2/4 reduce over r;
// r==0 lanes pack & store 8 B each (contiguous 64 B row).
__global__ __launch_bounds__(256) void k_agg64f(
        const int* __restrict__ rowptr, const int* __restrict__ csr,
        const uint4* __restrict__ hsb, const float* __restrict__ dinv,
        const float* __restrict__ b1, const float* __restrict__ W2,
        unsigned* __restrict__ hsb2, int n) {
    int wid = (blockIdx.x * blockDim.x + threadIdx.x) >> 6;
    int lane = threadIdx.x & 63;
    int q = lane >> 3, r = lane & 7;
    int d0 = wid * NPW;
    if (d0 >= n) return;
    // per-lane weights: w2r[i][jj] = W2[(8r+i)][4q+jj]; bias b1r[i] = b1[8r+i]
    float w2r[8][4];
    float b1r[8];
#pragma unroll
    for (int i = 0; i < 8; i++) {
        b1r[i] = b1[8 * r + i];
#pragma unroll
        for (int jj = 0; jj < 4; jj++)
            w2r[i][jj] = W2[(8 * r + i) * 32 + 4 * q + jj];
    }
    int dend = min(d0 + NPW, n);
    for (int d = d0; d < dend; d++) {
        int beg = rowptr[d], end = rowptr[d + 1];
        float acc[8];
#pragma unroll
        for (int i = 0; i < 8; i++) acc[i] = 0.f;
        int base = beg;
        for (; base + 16 <= end; base += 16) {
            int sA = csr[base + q];
            int sB = csr[base + 8 + q];
            uint4 wA = hsb[(size_t)sA * 8 + r];
            uint4 wB = hsb[(size_t)sB * 8 + r];
            ACC8(wA)
            ACC8(wB)
        }
        if (base + q < end) {
            uint4 wv = hsb[(size_t)csr[base + q] * 8 + r];
            ACC8(wv)
        }
        if (base + 8 + q < end) {
            uint4 wv = hsb[(size_t)csr[base + 8 + q] * 8 + r];
            ACC8(wv)
        }
#pragma unroll
        for (int i = 0; i < 8; i++) {
            acc[i] += __shfl_xor(acc[i], 8, 64);
            acc[i] += __shfl_xor(acc[i], 16, 64);
            acc[i] += __shfl_xor(acc[i], 32, 64);
        }
        uint4 wsf = hsb[(size_t)d * 8 + r];
        ACC8(wsf)
        float di = dinv[d];
        float v[8];
#pragma unroll
        for (int i = 0; i < 8; i++) v[i] = fmaxf(acc[i] * di + b1r[i], 0.f);
        // in-register gemm: h[jj] = partial of h2[4q+jj] over feats 8r..8r+7
        float h[4] = {0.f, 0.f, 0.f, 0.f};
#pragma unroll
        for (int i = 0; i < 8; i++)
#pragma unroll
            for (int jj = 0; jj < 4; jj++) h[jj] += v[i] * w2r[i][jj];
#pragma unroll
        for (int jj = 0; jj < 4; jj++) {
            h[jj] += __shfl_xor(h[jj], 1, 64);
            h[jj] += __shfl_xor(h[jj], 2, 64);
            h[jj] += __shfl_xor(h[jj], 4, 64);
        }
        if (r == 0) {
            unsigned p0 = pack_bf16(h[0] * di, h[1] * di);
            unsigned p1 = pack_bf16(h[2] * di, h[3] * di);
            *(uint2*)(hsb2 + (size_t)d * 16 + 2 * q) = make_uint2(p0, p1);
        }
    }
}

// Fused layer-2 aggregate + relu + 32x10 classifier + log_softmax -> out.
// Lane (q=lane>>2 in 0..15, r=lane&3). Gather: 4 lanes/row.
// After xor-4/8/16/32 reduce, all lanes hold feats 8r..8r+7 of summed row.
// Lane computes logit q partial (q<10); xor-1/2 reduce over r; 10 shfls
// broadcast all logits; r==0 && q<10 lanes write out[d*10+q].
__global__ __launch_bounds__(256) void k_agg32f(
        const int* __restrict__ rowptr, const int* __restrict__ csr,
        const uint4* __restrict__ hsb2, const float* __restrict__ dinv,
        const float* __restrict__ b2, const float* __restrict__ Wc,
        const float* __restrict__ bc, float* __restrict__ out, int n) {
    int wid = (blockIdx.x * blockDim.x + threadIdx.x) >> 6;
    int lane = threadIdx.x & 63;
    int q = lane >> 2, r = lane & 3;
    int d0 = wid * NPW;
    if (d0 >= n) return;
    float wcr[8];
    float b2r[8];
    float bcr = (q < 10) ? bc[q] : 0.f;
#pragma unroll
    for (int i = 0; i < 8; i++) {
        b2r[i] = b2[8 * r + i];
        wcr[i] = (q < 10) ? Wc[(8 * r + i) * 10 + q] : 0.f;
    }
    int dend = min(d0 + NPW, n);
    for (int d = d0; d < dend; d++) {
        int beg = rowptr[d], end = rowptr[d + 1];
        float acc[8];
#pragma unroll
        for (int i = 0; i < 8; i++) acc[i] = 0.f;
        int base = beg;
        for (; base + 32 <= end; base += 32) {
            int sA = csr[base + q];
            int sB = csr[base + 16 + q];
            uint4 wA = hsb2[(size_t)sA * 4 + r];
            uint4 wB = hsb2[(size_t)sB * 4 + r];
            ACC8(wA)
            ACC8(wB)
        }
        if (base + q < end) {
            uint4 wv = hsb2[(size_t)csr[base + q] * 4 + r];
            ACC8(wv)
        }
        if (base + 16 + q < end) {
            uint4 wv = hsb2[(size_t)csr[base + 16 + q] * 4 + r];
            ACC8(wv)
        }
#pragma unroll
        for (int i = 0; i < 8; i++) {
            acc[i] += __shfl_xor(acc[i], 4, 64);
            acc[i] += __shfl_xor(acc[i], 8, 64);
            acc[i] += __shfl_xor(acc[i], 16, 64);
            acc[i] += __shfl_xor(acc[i], 32, 64);
        }
        uint4 wsf = hsb2[(size_t)d * 4 + r];
        ACC8(wsf)
        float di = dinv[d];
        float part = 0.f;
#pragma unroll
        for (int i = 0; i < 8; i++) {
            float v = fmaxf(acc[i] * di + b2r[i], 0.f);
            part += v * wcr[i];
        }
        part += __shfl_xor(part, 1, 64);
        part += __shfl_xor(part, 2, 64);
        float mylogit = part + bcr;
        // broadcast all 10 logits (live in lanes 4c)
        float m = -1e30f;
        float l[10];
#pragma unroll
        for (int c = 0; c < 10; c++) {
            l[c] = __shfl(mylogit, 4 * c, 64);
            m = fmaxf(m, l[c]);
        }
        float ssum = 0.f;
#pragma unroll
        for (int c = 0; c < 10; c++) ssum += __expf(l[c] - m);
        float lse = m + __logf(ssum);
        if (r == 0 && q < 10) out[(size_t)d * 10 + q] = mylogit - lse;
    }
}

extern "C" void kernel_launch(void* const* d_in, const int* in_sizes, int n_in,
                              void* d_out, int out_size, void* d_ws, size_t ws_size,
                              hipStream_t stream) {
    const float* x  = (const float*)d_in[0];
    const int*   ei = (const int*)d_in[1];
    const float* W1 = (const float*)d_in[2];
    const float* b1 = (const float*)d_in[3];
    const float* W2 = (const float*)d_in[4];
    const float* b2 = (const float*)d_in[5];
    const float* Wc = (const float*)d_in[6];
    const float* bc = (const float*)d_in[7];
    float* out = (float*)d_out;

    const int N = in_sizes[0] / 128;
    const int E = in_sizes[1] / 2;
    const int* src = ei;
    const int* dst = ei + E;

    const int NBUCK = (N + BMASK) >> BSHIFT;   // <= 512
    const int NTILE = (E + TILE - 1) / TILE;
    const int NW = (N + NPW - 1) / NPW;        // waves for fused agg kernels

    char* ws = (char*)d_ws;
    size_t off = 0;
    auto alloc = [&](size_t elems) {
        void* p = ws + off;
        off += ((elems * 4 + 1023) & ~(size_t)1023);
        return p;
    };
    float*    dinv   = (float*)alloc(N);
    int*      bcnt   = (int*)alloc(NBUCK_MAX);
    int*      bbase  = (int*)alloc(NBUCK_MAX + 1);
    int*      gcur   = (int*)alloc(NBUCK_MAX);
    int*      rowptr = (int*)alloc(N + 1);
    int*      binned = (int*)alloc(E);
    int*      csr    = (int*)alloc(E);
    unsigned* hsb    = (unsigned*)alloc((size_t)N * 32);  // layer1 bf16 rows (128 B)
    unsigned* hsb2   = (unsigned*)alloc((size_t)N * 16);  // layer2 bf16 rows (64 B)

    hipMemsetAsync(bcnt, 0, sizeof(int) * NBUCK_MAX, stream);

    // CSR build
    k_hist<<<512, 256, 0, stream>>>(dst, bcnt, E);
    k_scanb<<<1, NBUCK_MAX, 0, stream>>>(bcnt, bbase, gcur, E);
    k_binA<<<NTILE, 256, 0, stream>>>(src, dst, gcur, binned, E);
    k_sortcsr<<<NBUCK, 256, 0, stream>>>(bbase, binned, rowptr, dinv, csr, N, E);

    // Layer 1: 128 -> 64 (R=2: 128 rows/block)
    k_gemm<128, 64, 2><<<(N + 127) / 128, 256, 0, stream>>>(x, W1, dinv, hsb, N);
    // Fused agg1 + relu + gemm2 -> hsb2
    k_agg64f<<<(NW * 64 + 255) / 256, 256, 0, stream>>>(rowptr, csr, (const uint4*)hsb,
                                                        dinv, b1, W2, hsb2, N);
    // Fused agg2 + relu + classifier + log_softmax -> out
    k_agg32f<<<(NW * 64 + 255) / 256, 256, 0, stream>>>(rowptr, csr, (const uint4*)hsb2,
                                                        dinv, b2, Wc, bc, out, N);
}